// Round 1
// baseline (1170.205 us; speedup 1.0000x reference)
//
#include <hip/hip_runtime.h>
#include <hip/hip_bf16.h>
#include <math.h>

#define T_TOK 2048
#define H_DIM 2048
#define I_DIM 1792
#define NEXP 16
#define TOPK 4

#define BM 128
#define BN 64
#define BK 32

typedef __attribute__((ext_vector_type(4))) float f4;
typedef __attribute__((ext_vector_type(4))) unsigned int u4;
typedef __attribute__((ext_vector_type(8))) short s8;

__device__ __forceinline__ unsigned short f2bf(float f) {
    union { float f; unsigned int u; } v; v.f = f;
    unsigned int u = v.u;
    return (unsigned short)((u + 0x7FFFu + ((u >> 16) & 1u)) >> 16); // RNE
}

// single-instruction packed fp32->bf16 (RNE), lo=a hi=b
__device__ __forceinline__ unsigned int cvtpk(float a, float b) {
    unsigned int r;
    asm("v_cvt_pk_bf16_f32 %0, %1, %2" : "=v"(r) : "v"(a), "v"(b));
    return r;
}

// async global->LDS 16B copy (dest = wave-uniform base + lane*16; our
// per-thread lds addr is exactly base + tid*16 within each wave)
__device__ __forceinline__ void async_copy16(const void* g, void* l) {
    __builtin_amdgcn_global_load_lds(
        (const __attribute__((address_space(1))) unsigned int*)g,
        (__attribute__((address_space(3))) unsigned int*)l, 16, 0, 0);
}

// ---- x fp32 -> bf16 ----
__global__ __launch_bounds__(256) void cvt_x_kernel(const float* __restrict__ x,
                                                    unsigned int* __restrict__ xb) {
    size_t i = ((size_t)blockIdx.x * 256 + threadIdx.x) * 8;
    f4 a = *(const f4*)(x + i);
    f4 b = *(const f4*)(x + i + 4);
    u4 o;
    o.x = cvtpk(a.x, a.y); o.y = cvtpk(a.z, a.w);
    o.z = cvtpk(b.x, b.y); o.w = cvtpk(b.z, b.w);
    *(u4*)(xb + i / 2) = o;
}

// ---- router: logits -> top4 -> normalized weights -> expert lists ----
__global__ __launch_bounds__(256) void router_kernel(
    const float* __restrict__ x, const float* __restrict__ rw,
    const float* __restrict__ bias, int* __restrict__ counts,
    int* __restrict__ etok, float* __restrict__ ew) {
    int t = blockIdx.x, tid = threadIdx.x;
    float acc[NEXP];
#pragma unroll
    for (int e = 0; e < NEXP; e++) acc[e] = 0.f;
    const float* xr = x + (size_t)t * H_DIM;
    for (int h = tid; h < H_DIM; h += 256) {
        float xv = xr[h];
#pragma unroll
        for (int e = 0; e < NEXP; e++) acc[e] += xv * rw[e * H_DIM + h];
    }
    __shared__ float red[4][NEXP];
    int lane = tid & 63, wid = tid >> 6;
#pragma unroll
    for (int e = 0; e < NEXP; e++) {
        float v = acc[e];
#pragma unroll
        for (int off = 32; off > 0; off >>= 1) v += __shfl_down(v, off, 64);
        if (lane == 0) red[wid][e] = v;
    }
    __syncthreads();
    if (tid == 0) {
        float logit[NEXP];
#pragma unroll
        for (int e = 0; e < NEXP; e++)
            logit[e] = red[0][e] + red[1][e] + red[2][e] + red[3][e] + bias[e];
        int idx[TOPK]; float lv[TOPK];
        unsigned picked = 0;
        for (int k = 0; k < TOPK; k++) {
            int best = 0; float bv = -1e30f;
            for (int e = 0; e < NEXP; e++) {
                if ((picked >> e) & 1) continue;
                if (logit[e] > bv) { bv = logit[e]; best = e; }
            }
            picked |= 1u << best; idx[k] = best; lv[k] = bv;
        }
        float m = lv[0], wsum = 0.f, w[TOPK];
        for (int k = 0; k < TOPK; k++) { w[k] = expf(lv[k] - m); wsum += w[k]; }
        for (int k = 0; k < TOPK; k++) {
            int e = idx[k];
            int slot = atomicAdd(&counts[e], 1);
            etok[e * T_TOK + slot] = t;
            ew[e * T_TOK + slot] = w[k] / wsum;
        }
    }
}

__global__ void offsets_kernel(const int* __restrict__ counts, int* __restrict__ offs) {
    if (threadIdx.x == 0 && blockIdx.x == 0) {
        int s = 0;
        for (int e = 0; e < NEXP; e++) { offs[e] = s; s += counts[e]; }
        offs[NEXP] = s;
    }
}

// ---- GEMM1: act[row] = silu(x@gate) * (x@up) * w_row, bf16, compact rows ----
__global__ __launch_bounds__(256, 2) void gemm1_kernel(
    const unsigned short* __restrict__ xb, const float* __restrict__ gate,
    const float* __restrict__ up, const int* __restrict__ counts,
    const int* __restrict__ offs, const int* __restrict__ etok,
    const float* __restrict__ ew, unsigned short* __restrict__ act) {
    int e = blockIdx.z;
    int cnt = counts[e];
    int m0 = blockIdx.y * BM;
    if (m0 >= cnt) return;
    int n0 = blockIdx.x * BN;
    int tid = threadIdx.x;
    int lane = tid & 63, w = tid >> 6;
    int wm = w >> 1, wn = w & 1;

    __shared__ unsigned short As[4 * BM * 8];   // [q][m][8]
    __shared__ unsigned short Bs1[4 * BN * 8];  // [q][n][8]
    __shared__ unsigned short Bs2[4 * BN * 8];
    __shared__ float wrow[BM];

    // A staging: slots s = tid, tid+256 ; m = s&127, q = s>>7
    int mA0 = tid & (BM - 1), qA0 = tid >> 7;
    int qA1 = qA0 + 2;
    int r0 = m0 + mA0; if (r0 >= cnt) r0 = m0; // safe row (reads masked later)
    int tok0 = etok[e * T_TOK + r0];
    const unsigned short* gA0 = xb + (size_t)tok0 * H_DIM + qA0 * 8;
    const unsigned short* gA1 = xb + (size_t)tok0 * H_DIM + qA1 * 8;
    unsigned short* lA0 = &As[(size_t)tid * 8];
    unsigned short* lA1 = &As[(size_t)(tid + 256) * 8];

    // B staging: thread covers (kk,kk+1) x (nn..nn+3)
    int nn = (tid & 15) * 4, kk = (tid >> 4) * 2;
    const float* gB1 = gate + (size_t)e * H_DIM * I_DIM + (size_t)kk * I_DIM + n0 + nn;
    const float* gB2 = up   + (size_t)e * H_DIM * I_DIM + (size_t)kk * I_DIM + n0 + nn;
    int qB = kk >> 3, jB = kk & 7;
    int ldsB = (qB * BN + nn) * 8 + jB; // element offset, jB even -> b32 aligned

    if (tid < BM) {
        int r = m0 + tid;
        wrow[tid] = (r < cnt) ? ew[e * T_TOK + r] : 0.f;
    }

    f4 accG[4][2], accU[4][2];
#pragma unroll
    for (int mi = 0; mi < 4; mi++)
#pragma unroll
        for (int ni = 0; ni < 2; ni++) {
            accG[mi][ni] = (f4)0.f; accU[mi][ni] = (f4)0.f;
        }

    int qf = lane >> 4, lf = lane & 15;
    for (int kt = 0; kt < H_DIM / BK; kt++) {
        int k0 = kt * BK;
        f4 b1a = *(const f4*)(gB1 + (size_t)k0 * I_DIM);
        f4 b1b = *(const f4*)(gB1 + (size_t)(k0 + 1) * I_DIM);
        f4 b2a = *(const f4*)(gB2 + (size_t)k0 * I_DIM);
        f4 b2b = *(const f4*)(gB2 + (size_t)(k0 + 1) * I_DIM);
        __syncthreads();
        async_copy16(gA0 + k0, lA0);   // direct global->LDS, lands by next barrier
        async_copy16(gA1 + k0, lA1);
#pragma unroll
        for (int i = 0; i < 4; i++) {
            *(unsigned int*)&Bs1[ldsB + i * 8] = cvtpk(b1a[i], b1b[i]);
            *(unsigned int*)&Bs2[ldsB + i * 8] = cvtpk(b2a[i], b2b[i]);
        }
        __syncthreads();
        s8 afr[4];
#pragma unroll
        for (int mi = 0; mi < 4; mi++) {
            int m = wm * 64 + mi * 16 + lf;
            afr[mi] = *(const s8*)&As[(qf * BM + m) * 8];
        }
#pragma unroll
        for (int ni = 0; ni < 2; ni++) {
            int n = wn * 32 + ni * 16 + lf;
            s8 b1 = *(const s8*)&Bs1[(qf * BN + n) * 8];
            s8 b2 = *(const s8*)&Bs2[(qf * BN + n) * 8];
#pragma unroll
            for (int mi = 0; mi < 4; mi++) {
                accG[mi][ni] = __builtin_amdgcn_mfma_f32_16x16x32_bf16(afr[mi], b1, accG[mi][ni], 0, 0, 0);
                accU[mi][ni] = __builtin_amdgcn_mfma_f32_16x16x32_bf16(afr[mi], b2, accU[mi][ni], 0, 0, 0);
            }
        }
    }

    int off_e = offs[e];
#pragma unroll
    for (int mi = 0; mi < 4; mi++) {
#pragma unroll
        for (int p = 0; p < 4; p++) {
            int ml = wm * 64 + mi * 16 + qf * 4 + p;
            int r = m0 + ml;
            if (r < cnt) {
                float wv = wrow[ml];
                size_t row = (size_t)(off_e + r);
#pragma unroll
                for (int ni = 0; ni < 2; ni++) {
                    float g = accG[mi][ni][p], u = accU[mi][ni][p];
                    float a = g / (1.f + expf(-g)) * u * wv;
                    int c = n0 + wn * 32 + ni * 16 + lf;
                    act[row * I_DIM + c] = f2bf(a);
                }
            }
        }
    }
}

// ---- GEMM2: out[token] += act @ down ----
__global__ __launch_bounds__(256, 2) void gemm2_kernel(
    const unsigned short* __restrict__ act, const float* __restrict__ down,
    const int* __restrict__ counts, const int* __restrict__ offs,
    const int* __restrict__ etok, float* __restrict__ out) {
    int e = blockIdx.z;
    int cnt = counts[e];
    int m0 = blockIdx.y * BM;
    if (m0 >= cnt) return;
    int n0 = blockIdx.x * BN;
    int tid = threadIdx.x;
    int lane = tid & 63, w = tid >> 6;
    int wm = w >> 1, wn = w & 1;
    int off_e = offs[e];

    __shared__ unsigned short As[4 * BM * 8];
    __shared__ unsigned short Bs[4 * BN * 8];

    int mA0 = tid & (BM - 1), qA0 = tid >> 7;
    int qA1 = qA0 + 2;
    int rr0 = m0 + mA0; if (rr0 >= cnt) rr0 = m0;
    const unsigned short* gA0 = act + (size_t)(off_e + rr0) * I_DIM + qA0 * 8;
    const unsigned short* gA1 = act + (size_t)(off_e + rr0) * I_DIM + qA1 * 8;
    unsigned short* lA0 = &As[(size_t)tid * 8];
    unsigned short* lA1 = &As[(size_t)(tid + 256) * 8];

    int nn = (tid & 15) * 4, kk = (tid >> 4) * 2;
    const float* gB = down + (size_t)e * I_DIM * H_DIM + (size_t)kk * H_DIM + n0 + nn;
    int qB = kk >> 3, jB = kk & 7;
    int ldsB = (qB * BN + nn) * 8 + jB;

    f4 acc[4][2];
#pragma unroll
    for (int mi = 0; mi < 4; mi++)
#pragma unroll
        for (int ni = 0; ni < 2; ni++) acc[mi][ni] = (f4)0.f;

    int qf = lane >> 4, lf = lane & 15;
    for (int kt = 0; kt < I_DIM / BK; kt++) {
        int k0 = kt * BK;
        f4 ba = *(const f4*)(gB + (size_t)k0 * H_DIM);
        f4 bb = *(const f4*)(gB + (size_t)(k0 + 1) * H_DIM);
        __syncthreads();
        async_copy16(gA0 + k0, lA0);
        async_copy16(gA1 + k0, lA1);
#pragma unroll
        for (int i = 0; i < 4; i++)
            *(unsigned int*)&Bs[ldsB + i * 8] = cvtpk(ba[i], bb[i]);
        __syncthreads();
        s8 afr[4];
#pragma unroll
        for (int mi = 0; mi < 4; mi++) {
            int m = wm * 64 + mi * 16 + lf;
            afr[mi] = *(const s8*)&As[(qf * BM + m) * 8];
        }
#pragma unroll
        for (int ni = 0; ni < 2; ni++) {
            int n = wn * 32 + ni * 16 + lf;
            s8 b = *(const s8*)&Bs[(qf * BN + n) * 8];
#pragma unroll
            for (int mi = 0; mi < 4; mi++)
                acc[mi][ni] = __builtin_amdgcn_mfma_f32_16x16x32_bf16(afr[mi], b, acc[mi][ni], 0, 0, 0);
        }
    }

#pragma unroll
    for (int mi = 0; mi < 4; mi++) {
#pragma unroll
        for (int p = 0; p < 4; p++) {
            int ml = wm * 64 + mi * 16 + qf * 4 + p;
            int r = m0 + ml;
            if (r < cnt) {
                int t = etok[e * T_TOK + r];
#pragma unroll
                for (int ni = 0; ni < 2; ni++) {
                    int c = n0 + wn * 32 + ni * 16 + lf;
                    atomicAdd(&out[(size_t)t * H_DIM + c], acc[mi][ni][p]);
                }
            }
        }
    }
}

extern "C" void kernel_launch(void* const* d_in, const int* in_sizes, int n_in,
                              void* d_out, int out_size, void* d_ws, size_t ws_size,
                              hipStream_t stream) {
    const float* x    = (const float*)d_in[0];
    const float* rw   = (const float*)d_in[1];
    const float* bias = (const float*)d_in[2];
    const float* gate = (const float*)d_in[3];
    const float* up   = (const float*)d_in[4];
    const float* down = (const float*)d_in[5];
    float* out = (float*)d_out;

    char* ws = (char*)d_ws;
    int*   counts = (int*)ws;                              // 64 B
    int*   offs   = (int*)(ws + 256);                      // 68 B
    int*   etok   = (int*)(ws + 512);                      // 128 KiB
    float* ew     = (float*)(ws + 512 + NEXP * T_TOK * 4); // 128 KiB
    unsigned int*   xb  = (unsigned int*)(ws + 262656);    // 8 MiB (bf16 x)
    unsigned short* act = (unsigned short*)(ws + 8651264); // 28 MiB (bf16 act)

    hipMemsetAsync(out, 0, (size_t)T_TOK * H_DIM * sizeof(float), stream);
    hipMemsetAsync(counts, 0, NEXP * sizeof(int), stream);
    cvt_x_kernel<<<(T_TOK * H_DIM) / (256 * 8), 256, 0, stream>>>(x, xb);
    router_kernel<<<T_TOK, 256, 0, stream>>>(x, rw, bias, counts, etok, ew);
    offsets_kernel<<<1, 64, 0, stream>>>(counts, offs);
    gemm1_kernel<<<dim3(I_DIM / BN, T_TOK / BM, NEXP), 256, 0, stream>>>(
        (const unsigned short*)xb, gate, up, counts, offs, etok, ew, act);
    gemm2_kernel<<<dim3(H_DIM / BN, T_TOK / BM, NEXP), 256, 0, stream>>>(
        act, down, counts, offs, etok, out);
}